// Round 2
// baseline (194.034 us; speedup 1.0000x reference)
//
#include <hip/hip_runtime.h>

#define IN_CH 16
#define OUT_CH 16
#define EDGE_FEAT 32
#define HIDDEN 128
#define WROW 256          // IN_CH*OUT_CH
#define FN_FPB 16         // filters per block in filter-net kernel
#define WSLOTS 64         // per-wave run slots
#define LSTR 16           // LDS floats per slot (16 channels; deg derived)

typedef __fp16 half2_v __attribute__((ext_vector_type(2)));
typedef unsigned uvec4 __attribute__((ext_vector_type(4)));
typedef float fvec4 __attribute__((ext_vector_type(4)));

typedef const __attribute__((address_space(1))) void* gas_ptr;
typedef __attribute__((address_space(3))) void* las_ptr;

__device__ __forceinline__ unsigned pk_f16(float lo, float hi) {
  half2_v h = __builtin_amdgcn_cvt_pkrtz(lo, hi);
  return __builtin_bit_cast(unsigned, h);
}

__device__ __forceinline__ float dot2(unsigned wpair, half2_v xp, float acc) {
  half2_v w = __builtin_bit_cast(half2_v, wpair);
#if __has_builtin(__builtin_amdgcn_fdot2)
  return __builtin_amdgcn_fdot2(xp, w, acc, false);
#else
  acc = fmaf((float)xp[0], (float)w[0], acc);
  return fmaf((float)xp[1], (float)w[1], acc);
#endif
}

// ---------------- Kernel 1: filter net v2 (r14, measured -7 µs) -------------
__global__ __launch_bounds__(256) void filter_net_kernel(
    const float* __restrict__ ef, const float* __restrict__ W1,
    const float* __restrict__ b1, const float* __restrict__ W2,
    const float* __restrict__ b2, unsigned short* __restrict__ weights,
    float* __restrict__ zero_base, int nzero4) {
  const int t = threadIdx.x;
  const int f0 = blockIdx.x * FN_FPB;

  for (int gid = blockIdx.x * 256 + t; gid < nzero4; gid += gridDim.x * 256)
    ((float4*)zero_base)[gid] = make_float4(0.f, 0.f, 0.f, 0.f);

  __shared__ float ef_s[FN_FPB * EDGE_FEAT];   // 2 KB
  __shared__ float h_s[FN_FPB][HIDDEN];        // 8 KB
  ef_s[t] = ef[f0 * EDGE_FEAT + t];
  ef_s[t + 256] = ef[f0 * EDGE_FEAT + t + 256];
  __syncthreads();

  // stage 1: 2048 h values, 8 per thread.
  {
    const int hi = t & 127;
    const int fb = (t >> 7) * 8;
    float a[8];
    #pragma unroll
    for (int r = 0; r < 8; ++r) a[r] = b1[hi];
    for (int k0 = 0; k0 < EDGE_FEAT; k0 += 4) {
      float w1v[4];
      #pragma unroll
      for (int m = 0; m < 4; ++m) w1v[m] = W1[(k0 + m) * HIDDEN + hi];
      #pragma unroll
      for (int r = 0; r < 8; ++r) {
        const float4 e4 = *(const float4*)&ef_s[(fb + r) * EDGE_FEAT + k0];
        a[r] = fmaf(e4.x, w1v[0], a[r]);
        a[r] = fmaf(e4.y, w1v[1], a[r]);
        a[r] = fmaf(e4.z, w1v[2], a[r]);
        a[r] = fmaf(e4.w, w1v[3], a[r]);
      }
    }
    #pragma unroll
    for (int r = 0; r < 8; ++r) h_s[fb + r][hi] = a[r] > 0.f ? a[r] : 0.f;
  }
  __syncthreads();

  // stage 2: cq owns cols 4cq..4cq+3 for filters grp*4..grp*4+3.
  const int cq = t & 63;
  const int grp = t >> 6;
  float4 facc[4];
  const float4 bb = *(const float4*)(b2 + 4 * cq);
  #pragma unroll
  for (int q = 0; q < 4; ++q) facc[q] = bb;
  for (int k0 = 0; k0 < HIDDEN; k0 += 4) {
    float4 w2v[4];
    #pragma unroll
    for (int m = 0; m < 4; ++m)
      w2v[m] = ((const float4*)(W2 + (size_t)(k0 + m) * WROW))[cq];
    #pragma unroll
    for (int q = 0; q < 4; ++q) {
      const float4 h4 = *(const float4*)&h_s[grp * 4 + q][k0];
      facc[q].x = fmaf(h4.x, w2v[0].x, facc[q].x);
      facc[q].y = fmaf(h4.x, w2v[0].y, facc[q].y);
      facc[q].z = fmaf(h4.x, w2v[0].z, facc[q].z);
      facc[q].w = fmaf(h4.x, w2v[0].w, facc[q].w);
      facc[q].x = fmaf(h4.y, w2v[1].x, facc[q].x);
      facc[q].y = fmaf(h4.y, w2v[1].y, facc[q].y);
      facc[q].z = fmaf(h4.y, w2v[1].z, facc[q].z);
      facc[q].w = fmaf(h4.y, w2v[1].w, facc[q].w);
      facc[q].x = fmaf(h4.z, w2v[2].x, facc[q].x);
      facc[q].y = fmaf(h4.z, w2v[2].y, facc[q].y);
      facc[q].z = fmaf(h4.z, w2v[2].z, facc[q].z);
      facc[q].w = fmaf(h4.z, w2v[2].w, facc[q].w);
      facc[q].x = fmaf(h4.w, w2v[3].x, facc[q].x);
      facc[q].y = fmaf(h4.w, w2v[3].y, facc[q].y);
      facc[q].z = fmaf(h4.w, w2v[3].z, facc[q].z);
      facc[q].w = fmaf(h4.w, w2v[3].w, facc[q].w);
    }
  }

  const int i = cq >> 2;
  const int jo = cq & 3;
  const int u = i >> 1;
  #pragma unroll
  for (int q = 0; q < 4; ++q) {
    float4 oth;
    oth.x = __shfl_xor(facc[q].x, 4);
    oth.y = __shfl_xor(facc[q].y, 4);
    oth.z = __shfl_xor(facc[q].z, 4);
    oth.w = __shfl_xor(facc[q].w, 4);
    if ((i & 1) == 0) {
      uint4 st;
      st.x = pk_f16(facc[q].x, oth.x);
      st.y = pk_f16(facc[q].y, oth.y);
      st.z = pk_f16(facc[q].z, oth.z);
      st.w = pk_f16(facc[q].w, oth.w);
      *(uint4*)(weights + (size_t)(f0 + grp * 4 + q) * WROW +
                (u * 4 + jo) * 8) = st;
    }
  }
}

// ---------------- Kernel 2: edge kernel r18 — global_load_lds staging -------
// r17 post-mortem: VGPR=52 proved the compiler re-sank register prefetch
// (can't hold 2x32-reg wv buffers) — register pipelines are unwinnable here.
// r18: weight rows DMA'd to LDS via global_load_lds width=16 (zero VGPR
// cost, nothing to sink), double-buffered 16-edge chunks, counted vmcnt(8)
// waits (never 0 mid-loop). Per-lane GLOBAL address carries the gather plus
// a 16B XOR pre-swizzle; LDS dest linear (both-sides-or-neither). ds_read
// side applies the same XOR -> 8 dwords/bank = conflict-free minimum.
// Compute path (DPP broadcast + fdot2 + seg DPP scan) byte-identical to r15.
template <int CTRL, int OLD>
__device__ __forceinline__ int dpp_i(int v) {
  return __builtin_amdgcn_update_dpp(OLD, v, CTRL, 0xf, 0xf, false);
}
template <int CTRL>
__device__ __forceinline__ float dpp_f(float v) {
  return __builtin_bit_cast(
      float, __builtin_amdgcn_update_dpp(0, __builtin_bit_cast(int, v), CTRL,
                                         0xf, 0xf, false));
}
template <int Q>
__device__ __forceinline__ int quad_bcast_dpp(int v) {
  return __builtin_amdgcn_update_dpp(0, v, Q * 0x55, 0xf, 0xf, false);
}

template <int CTRL>
__device__ __forceinline__ void seg_step_dpp(int sl, fvec4& acc) {
  const int os = dpp_i<CTRL, -1>(sl);
  const float ox = dpp_f<CTRL>(acc.x);
  const float oy = dpp_f<CTRL>(acc.y);
  const float oz = dpp_f<CTRL>(acc.z);
  const float ow = dpp_f<CTRL>(acc.w);
  if (os == sl) {
    acc.x += ox; acc.y += oy; acc.z += oz; acc.w += ow;
  }
}

// Stage one 16-edge phase (8 KB) into an LDS buffer: 8 DMA instructions,
// each 64 lanes x 16B = 1 KB = rows {2k, 2k+1}. Lane l covers row
// 2k + (l>>5), dest byte (l&31)*16 (linear); global src pre-swizzled.
__device__ __forceinline__ void stage_phase(
    const unsigned short* __restrict__ weights, int f_l, int g, int lane,
    unsigned* buf) {
  const int half = lane >> 5;
  const int dq = (lane & 31) << 4;
  #pragma unroll
  for (int k = 0; k < 8; ++k) {
    const int row = 2 * k + half;
    const int fs = __shfl(f_l, g * 16 + row);
    const char* src = (const char*)weights + ((size_t)fs << 9) +
                      (dq ^ ((row & 7) << 4));
    __builtin_amdgcn_global_load_lds((gas_ptr)src,
                                     (las_ptr)((char*)buf + (k << 10)),
                                     16, 0, 0);
  }
}

__device__ __forceinline__ void do_phase_lds(
    const fvec4 xo, const unsigned* buf, const int e16, const int j,
    const int sl, const bool ve, float* __restrict__ acc_w) {
  const int p0 = (int)pk_f16(xo.x, xo.y);
  const int p1 = (int)pk_f16(xo.z, xo.w);
  half2_v xp[8];
  xp[0] = __builtin_bit_cast(half2_v, quad_bcast_dpp<0>(p0));
  xp[1] = __builtin_bit_cast(half2_v, quad_bcast_dpp<0>(p1));
  xp[2] = __builtin_bit_cast(half2_v, quad_bcast_dpp<1>(p0));
  xp[3] = __builtin_bit_cast(half2_v, quad_bcast_dpp<1>(p1));
  xp[4] = __builtin_bit_cast(half2_v, quad_bcast_dpp<2>(p0));
  xp[5] = __builtin_bit_cast(half2_v, quad_bcast_dpp<2>(p1));
  xp[6] = __builtin_bit_cast(half2_v, quad_bcast_dpp<3>(p0));
  xp[7] = __builtin_bit_cast(half2_v, quad_bcast_dpp<3>(p1));

  const char* wb = (const char*)buf + (e16 << 9);
  const int swz = (e16 & 7) << 4;
  fvec4 acc = {0.f, 0.f, 0.f, 0.f};
  #pragma unroll
  for (int u = 0; u < 8; ++u) {
    const uvec4 wv = *(const uvec4*)(wb + (((u << 6) | (j << 4)) ^ swz));
    acc.x = dot2(wv.x, xp[u], acc.x);
    acc.y = dot2(wv.y, xp[u], acc.y);
    acc.z = dot2(wv.z, xp[u], acc.z);
    acc.w = dot2(wv.w, xp[u], acc.w);
  }
  if (!ve) { acc.x = 0.f; acc.y = 0.f; acc.z = 0.f; acc.w = 0.f; }

  seg_step_dpp<0x104>(sl, acc);            // + next edge (within row)
  seg_step_dpp<0x108>(sl, acc);            // + edges +2,+3
  const int pslot = dpp_i<0x114, -1>(sl);  // prev edge's slot
  if (ve && pslot != sl) {                 // sub-run head -> LDS accumulate
    float* p = acc_w + sl * LSTR + j * 4;
    atomicAdd(p + 0, acc.x);
    atomicAdd(p + 1, acc.y);
    atomicAdd(p + 2, acc.z);
    atomicAdd(p + 3, acc.w);
  }
}

__global__ __launch_bounds__(64) void edge_kernel(
    const float* __restrict__ input, const int* __restrict__ idxn,
    const int* __restrict__ idxe, const int* __restrict__ seg,
    const unsigned short* __restrict__ weights, float* __restrict__ sums,
    float* __restrict__ deg, int n_edges) {
  __shared__ float lds_acc[WSLOTS * LSTR];              // 4 KB
  __shared__ int lds_map[WSLOTS];                       // 256 B
  __shared__ __align__(16) unsigned wstage[2][2048];    // 2 x 8 KB dbuf

  const int lane = threadIdx.x;
  const int e16 = lane >> 2;
  const int j = lane & 3;
  float* __restrict__ acc_w = lds_acc;

  const long wv_base = (long)blockIdx.x * 64;
  long rem = n_edges - wv_base;
  const int valid_cnt = rem < 0 ? 0 : (rem > 64 ? 64 : (int)rem);

  long el = wv_base + lane;
  const bool vl = el < n_edges;
  if (!vl) el = n_edges - 1;
  const int s_l = seg[el];
  const int n_l = idxn[el];
  const int f_l = idxe[el];
  const int sv = vl ? s_l : -1;

  // x gather for all 4 phases, issued before staging (retires first; the
  // vmcnt(8) below therefore also guarantees x is in regs).
  int ngv[4];
  #pragma unroll
  for (int g = 0; g < 4; ++g) ngv[g] = __shfl(n_l, g * 16 + e16);
  fvec4 xov[4];
  #pragma unroll
  for (int g = 0; g < 4; ++g)
    xov[g] = *(const fvec4*)(input + ((size_t)ngv[g] << 4) + (j << 2));

  // prologue: phases 0,1 in flight.
  stage_phase(weights, f_l, 0, lane, &wstage[0][0]);
  stage_phase(weights, f_l, 1, lane, &wstage[1][0]);

  // slot bookkeeping overlaps the DMA (VALU/DS only).
  const int sprev = __shfl(sv, (lane - 1) & 63);
  const bool head = vl && (lane == 0 || sprev != sv);
  const unsigned long long bal = __ballot(head);
  const int r = (int)__popcll(bal & ((1ull << lane) - 1ull));
  const int r_w = (int)__popcll(bal);

  for (int idx = lane; idx < r_w * LSTR; idx += 64) acc_w[idx] = 0.f;

  const int slot_l = r - (head ? 0 : 1);
  if (head) lds_map[slot_l] = (lane << 20) | sv;   // head lane | node id

  int slv[4];
  #pragma unroll
  for (int g = 0; g < 4; ++g) slv[g] = __shfl(slot_l, g * 16 + e16);

  // steady state: compute g (stage g+1 stays in flight), then reuse g's
  // buffer for stage g+2. vmcnt never drained to 0 until the last phase.
  asm volatile("s_waitcnt vmcnt(8)" ::: "memory");   // x + stage0 done
  do_phase_lds(xov[0], &wstage[0][0], e16, j, slv[0], e16 < valid_cnt, acc_w);
  asm volatile("" ::: "memory");                     // keep DMA after reads
  stage_phase(weights, f_l, 2, lane, &wstage[0][0]);

  asm volatile("s_waitcnt vmcnt(8)" ::: "memory");   // stage1 done
  do_phase_lds(xov[1], &wstage[1][0], e16, j, slv[1], 16 + e16 < valid_cnt,
               acc_w);
  asm volatile("" ::: "memory");
  stage_phase(weights, f_l, 3, lane, &wstage[1][0]);

  asm volatile("s_waitcnt vmcnt(8)" ::: "memory");   // stage2 done
  do_phase_lds(xov[2], &wstage[0][0], e16, j, slv[2], 32 + e16 < valid_cnt,
               acc_w);

  asm volatile("s_waitcnt vmcnt(0)" ::: "memory");   // stage3 done (last)
  do_phase_lds(xov[3], &wstage[1][0], e16, j, slv[3], 48 + e16 < valid_cnt,
               acc_w);

  // drain wave-local DS before reading slots (no barrier: wave-private).
  asm volatile("s_waitcnt lgkmcnt(0)" ::: "memory");

  // flush; deg derived from head-lane deltas (no cnt accumulation).
  const int ch = lane & 15;
  for (int slot = lane >> 4; slot < r_w; slot += 4) {
    const int m0 = lds_map[slot];
    const int node = m0 & 0xFFFFF;
    atomicAdd(sums + ((size_t)node << 4) + ch, acc_w[slot * LSTR + ch]);
    if (ch == 0) {
      const int start = m0 >> 20;
      const int end =
          (slot + 1 < r_w) ? (lds_map[slot + 1] >> 20) : valid_cnt;
      atomicAdd(deg + node, (float)(end - start));
    }
  }
}

// ---------------- Kernel 3: divide by degree --------------------------------
__global__ __launch_bounds__(256) void finalize_kernel(
    const float* __restrict__ sums, const float* __restrict__ deg,
    float* __restrict__ out, int n_nodes) {
  const int n = blockIdx.x * blockDim.x + threadIdx.x;
  if (n >= n_nodes) return;
  const float d = deg[n];
  const float scale = d > 0.f ? 1.f / d : 0.f;
  const float4* sp = (const float4*)(sums + (size_t)n * OUT_CH);
  float4* op = (float4*)(out + (size_t)n * OUT_CH);
  #pragma unroll
  for (int q = 0; q < 4; ++q) {
    float4 v = sp[q];
    v.x *= scale; v.y *= scale; v.z *= scale; v.w *= scale;
    op[q] = v;
  }
}

extern "C" void kernel_launch(void* const* d_in, const int* in_sizes, int n_in,
                              void* d_out, int out_size, void* d_ws, size_t ws_size,
                              hipStream_t stream) {
  const float* input = (const float*)d_in[0];
  const int* idxn    = (const int*)d_in[1];
  const int* idxe    = (const int*)d_in[2];
  const int* seg     = (const int*)d_in[3];
  const float* ef    = (const float*)d_in[4];
  const float* W1    = (const float*)d_in[5];
  const float* b1    = (const float*)d_in[6];
  const float* W2    = (const float*)d_in[7];
  const float* b2    = (const float*)d_in[8];
  float* out = (float*)d_out;

  const int n_nodes   = in_sizes[0] / IN_CH;
  const int n_edges   = in_sizes[1];
  const int n_filters = in_sizes[4] / EDGE_FEAT;

  // workspace: f16 weights [F*256] (2 MB) | sums [n_nodes*16] | deg [n_nodes]
  unsigned short* weights = (unsigned short*)d_ws;
  float* sums = (float*)((char*)d_ws + (size_t)n_filters * WROW * sizeof(unsigned short));
  float* deg  = sums + (size_t)n_nodes * OUT_CH;

  const int nzero4 = (n_nodes * (OUT_CH + 1)) / 4;
  filter_net_kernel<<<n_filters / FN_FPB, 256, 0, stream>>>(
      ef, W1, b1, W2, b2, weights, sums, nzero4);

  const long n_blocks = ((long)n_edges + 63) / 64;
  edge_kernel<<<(int)n_blocks, 64, 0, stream>>>(
      input, idxn, idxe, seg, weights, sums, deg, n_edges);

  finalize_kernel<<<(n_nodes + 255) / 256, 256, 0, stream>>>(sums, deg, out,
                                                             n_nodes);
}

// Round 3
// 143.973 us; speedup vs baseline: 1.3477x; 1.3477x over previous
//
#include <hip/hip_runtime.h>

#define IN_CH 16
#define OUT_CH 16
#define EDGE_FEAT 32
#define HIDDEN 128
#define WROW 256          // IN_CH*OUT_CH
#define FN_FPB 16         // filters per block in filter-net kernel
#define WSLOTS 64         // per-wave run slots
#define LSTR 16           // LDS floats per slot (16 channels; deg derived)

typedef __fp16 half2_v __attribute__((ext_vector_type(2)));
typedef unsigned uvec4 __attribute__((ext_vector_type(4)));
typedef float fvec4 __attribute__((ext_vector_type(4)));

__device__ __forceinline__ unsigned pk_f16(float lo, float hi) {
  half2_v h = __builtin_amdgcn_cvt_pkrtz(lo, hi);
  return __builtin_bit_cast(unsigned, h);
}

__device__ __forceinline__ float dot2(unsigned wpair, half2_v xp, float acc) {
  half2_v w = __builtin_bit_cast(half2_v, wpair);
#if __has_builtin(__builtin_amdgcn_fdot2)
  return __builtin_amdgcn_fdot2(xp, w, acc, false);
#else
  acc = fmaf((float)xp[0], (float)w[0], acc);
  return fmaf((float)xp[1], (float)w[1], acc);
#endif
}

// ---------------- Kernel 1: filter net v2 (r14, measured -7 µs) -------------
__global__ __launch_bounds__(256) void filter_net_kernel(
    const float* __restrict__ ef, const float* __restrict__ W1,
    const float* __restrict__ b1, const float* __restrict__ W2,
    const float* __restrict__ b2, unsigned short* __restrict__ weights,
    float* __restrict__ zero_base, int nzero4) {
  const int t = threadIdx.x;
  const int f0 = blockIdx.x * FN_FPB;

  for (int gid = blockIdx.x * 256 + t; gid < nzero4; gid += gridDim.x * 256)
    ((float4*)zero_base)[gid] = make_float4(0.f, 0.f, 0.f, 0.f);

  __shared__ float ef_s[FN_FPB * EDGE_FEAT];   // 2 KB
  __shared__ float h_s[FN_FPB][HIDDEN];        // 8 KB
  ef_s[t] = ef[f0 * EDGE_FEAT + t];
  ef_s[t + 256] = ef[f0 * EDGE_FEAT + t + 256];
  __syncthreads();

  // stage 1: 2048 h values, 8 per thread.
  {
    const int hi = t & 127;
    const int fb = (t >> 7) * 8;
    float a[8];
    #pragma unroll
    for (int r = 0; r < 8; ++r) a[r] = b1[hi];
    for (int k0 = 0; k0 < EDGE_FEAT; k0 += 4) {
      float w1v[4];
      #pragma unroll
      for (int m = 0; m < 4; ++m) w1v[m] = W1[(k0 + m) * HIDDEN + hi];
      #pragma unroll
      for (int r = 0; r < 8; ++r) {
        const float4 e4 = *(const float4*)&ef_s[(fb + r) * EDGE_FEAT + k0];
        a[r] = fmaf(e4.x, w1v[0], a[r]);
        a[r] = fmaf(e4.y, w1v[1], a[r]);
        a[r] = fmaf(e4.z, w1v[2], a[r]);
        a[r] = fmaf(e4.w, w1v[3], a[r]);
      }
    }
    #pragma unroll
    for (int r = 0; r < 8; ++r) h_s[fb + r][hi] = a[r] > 0.f ? a[r] : 0.f;
  }
  __syncthreads();

  // stage 2: cq owns cols 4cq..4cq+3 for filters grp*4..grp*4+3.
  const int cq = t & 63;
  const int grp = t >> 6;
  float4 facc[4];
  const float4 bb = *(const float4*)(b2 + 4 * cq);
  #pragma unroll
  for (int q = 0; q < 4; ++q) facc[q] = bb;
  for (int k0 = 0; k0 < HIDDEN; k0 += 4) {
    float4 w2v[4];
    #pragma unroll
    for (int m = 0; m < 4; ++m)
      w2v[m] = ((const float4*)(W2 + (size_t)(k0 + m) * WROW))[cq];
    #pragma unroll
    for (int q = 0; q < 4; ++q) {
      const float4 h4 = *(const float4*)&h_s[grp * 4 + q][k0];
      facc[q].x = fmaf(h4.x, w2v[0].x, facc[q].x);
      facc[q].y = fmaf(h4.x, w2v[0].y, facc[q].y);
      facc[q].z = fmaf(h4.x, w2v[0].z, facc[q].z);
      facc[q].w = fmaf(h4.x, w2v[0].w, facc[q].w);
      facc[q].x = fmaf(h4.y, w2v[1].x, facc[q].x);
      facc[q].y = fmaf(h4.y, w2v[1].y, facc[q].y);
      facc[q].z = fmaf(h4.y, w2v[1].z, facc[q].z);
      facc[q].w = fmaf(h4.y, w2v[1].w, facc[q].w);
      facc[q].x = fmaf(h4.z, w2v[2].x, facc[q].x);
      facc[q].y = fmaf(h4.z, w2v[2].y, facc[q].y);
      facc[q].z = fmaf(h4.z, w2v[2].z, facc[q].z);
      facc[q].w = fmaf(h4.z, w2v[2].w, facc[q].w);
      facc[q].x = fmaf(h4.w, w2v[3].x, facc[q].x);
      facc[q].y = fmaf(h4.w, w2v[3].y, facc[q].y);
      facc[q].z = fmaf(h4.w, w2v[3].z, facc[q].z);
      facc[q].w = fmaf(h4.w, w2v[3].w, facc[q].w);
    }
  }

  const int i = cq >> 2;
  const int jo = cq & 3;
  const int u = i >> 1;
  #pragma unroll
  for (int q = 0; q < 4; ++q) {
    float4 oth;
    oth.x = __shfl_xor(facc[q].x, 4);
    oth.y = __shfl_xor(facc[q].y, 4);
    oth.z = __shfl_xor(facc[q].z, 4);
    oth.w = __shfl_xor(facc[q].w, 4);
    if ((i & 1) == 0) {
      uint4 st;
      st.x = pk_f16(facc[q].x, oth.x);
      st.y = pk_f16(facc[q].y, oth.y);
      st.z = pk_f16(facc[q].z, oth.z);
      st.w = pk_f16(facc[q].w, oth.w);
      *(uint4*)(weights + (size_t)(f0 + grp * 4 + q) * WROW +
                (u * 4 + jo) * 8) = st;
    }
  }
}

// ---------------- Kernel 2: edge kernel r19 — asm-forced depth-2 MLP --------
// r17 post-mortem: compiler re-sinks register prefetch (VGPR stayed 52).
// r18 post-mortem: 1-wave LDS-staged blocks collapsed occupancy to 18% and
// added 3.2M bank conflicts — structure reverted.
// r19: r15's 256-thread/4-wave structure, but weight+x loads issued as
// inline-asm global_load_dwordx4 (SGPR base + 32b voffset + imm offset).
// asm volatile loads cannot be re-sunk or elided -> forced depth-2 pipeline
// with counted s_waitcnt vmcnt(9) (never 0 mid-loop) + sched_barrier(0)
// fences (rule #18). All compiler vmem is consumed before the asm region and
// the flush atomics sit after an asm vmcnt(0), so hw vmcnt counts only ours.
template <int CTRL, int OLD>
__device__ __forceinline__ int dpp_i(int v) {
  return __builtin_amdgcn_update_dpp(OLD, v, CTRL, 0xf, 0xf, false);
}
template <int CTRL>
__device__ __forceinline__ float dpp_f(float v) {
  return __builtin_bit_cast(
      float, __builtin_amdgcn_update_dpp(0, __builtin_bit_cast(int, v), CTRL,
                                         0xf, 0xf, false));
}
template <int Q>
__device__ __forceinline__ int quad_bcast_dpp(int v) {
  return __builtin_amdgcn_update_dpp(0, v, Q * 0x55, 0xf, 0xf, false);
}

template <int CTRL>
__device__ __forceinline__ void seg_step_dpp(int sl, fvec4& acc) {
  const int os = dpp_i<CTRL, -1>(sl);
  const float ox = dpp_f<CTRL>(acc.x);
  const float oy = dpp_f<CTRL>(acc.y);
  const float oz = dpp_f<CTRL>(acc.z);
  const float ow = dpp_f<CTRL>(acc.w);
  if (os == sl) {
    acc.x += ox; acc.y += oy; acc.z += oz; acc.w += ow;
  }
}

template <int IOFF>
__device__ __forceinline__ uvec4 ldw16(const unsigned short* base,
                                       unsigned voff) {
  uvec4 r;
  asm volatile("global_load_dwordx4 %0, %1, %2 offset:%3"
               : "=v"(r)
               : "v"(voff), "s"(base), "i"(IOFF));
  return r;
}

__device__ __forceinline__ fvec4 ldxf4(const float* base, unsigned voff) {
  fvec4 r;
  asm volatile("global_load_dwordx4 %0, %1, %2"
               : "=v"(r)
               : "v"(voff), "s"(base));
  return r;
}

#define ISSUE_GROUP(g, wv, xo)                  \
  do {                                          \
    xo = ldxf4(input, xoff[g]);                 \
    wv[0] = ldw16<0>(weights, woff[g]);         \
    wv[1] = ldw16<64>(weights, woff[g]);        \
    wv[2] = ldw16<128>(weights, woff[g]);       \
    wv[3] = ldw16<192>(weights, woff[g]);       \
    wv[4] = ldw16<256>(weights, woff[g]);       \
    wv[5] = ldw16<320>(weights, woff[g]);       \
    wv[6] = ldw16<384>(weights, woff[g]);       \
    wv[7] = ldw16<448>(weights, woff[g]);       \
  } while (0)

#define VMWAIT(N)                                          \
  asm volatile("s_waitcnt vmcnt(" #N ")" ::: "memory");    \
  __builtin_amdgcn_sched_barrier(0)

__device__ __forceinline__ void do_phase(const fvec4 xo, const uvec4* wv,
                                         const int sl, const bool ve,
                                         const int j,
                                         float* __restrict__ acc_w) {
  const int p0 = (int)pk_f16(xo.x, xo.y);
  const int p1 = (int)pk_f16(xo.z, xo.w);
  half2_v xp[8];
  xp[0] = __builtin_bit_cast(half2_v, quad_bcast_dpp<0>(p0));
  xp[1] = __builtin_bit_cast(half2_v, quad_bcast_dpp<0>(p1));
  xp[2] = __builtin_bit_cast(half2_v, quad_bcast_dpp<1>(p0));
  xp[3] = __builtin_bit_cast(half2_v, quad_bcast_dpp<1>(p1));
  xp[4] = __builtin_bit_cast(half2_v, quad_bcast_dpp<2>(p0));
  xp[5] = __builtin_bit_cast(half2_v, quad_bcast_dpp<2>(p1));
  xp[6] = __builtin_bit_cast(half2_v, quad_bcast_dpp<3>(p0));
  xp[7] = __builtin_bit_cast(half2_v, quad_bcast_dpp<3>(p1));

  fvec4 acc = {0.f, 0.f, 0.f, 0.f};
  #pragma unroll
  for (int u = 0; u < 8; ++u) {
    acc.x = dot2(wv[u].x, xp[u], acc.x);
    acc.y = dot2(wv[u].y, xp[u], acc.y);
    acc.z = dot2(wv[u].z, xp[u], acc.z);
    acc.w = dot2(wv[u].w, xp[u], acc.w);
  }
  if (!ve) { acc.x = 0.f; acc.y = 0.f; acc.z = 0.f; acc.w = 0.f; }

  seg_step_dpp<0x104>(sl, acc);            // + next edge (within row)
  seg_step_dpp<0x108>(sl, acc);            // + edges +2,+3
  const int pslot = dpp_i<0x114, -1>(sl);  // prev edge's slot
  if (ve && pslot != sl) {                 // sub-run head -> LDS accumulate
    float* p = acc_w + sl * LSTR + j * 4;
    atomicAdd(p + 0, acc.x);
    atomicAdd(p + 1, acc.y);
    atomicAdd(p + 2, acc.z);
    atomicAdd(p + 3, acc.w);
  }
}

__global__ __launch_bounds__(256, 4) void edge_kernel(
    const float* __restrict__ input, const int* __restrict__ idxn,
    const int* __restrict__ idxe, const int* __restrict__ seg,
    const unsigned short* __restrict__ weights, float* __restrict__ sums,
    float* __restrict__ deg, int n_edges) {
  __shared__ float lds_acc[4][WSLOTS * LSTR];   // 4 x 4 KB (wave-private)
  __shared__ int lds_map[4][WSLOTS];

  const int t = threadIdx.x;
  const int lane = t & 63;
  const int w = t >> 6;
  const int e16 = lane >> 2;
  const int j = lane & 3;
  float* __restrict__ acc_w = lds_acc[w];

  const long wv_base = (long)blockIdx.x * 256 + w * 64;
  long rem = n_edges - wv_base;
  const int valid_cnt = rem < 0 ? 0 : (rem > 64 ? 64 : (int)rem);

  long el = wv_base + lane;
  const bool vl = el < n_edges;
  if (!vl) el = n_edges - 1;
  const int s_l = seg[el];
  const int n_l = idxn[el];
  const int f_l = idxe[el];
  const int sv = vl ? s_l : -1;

  // ---- bookkeeping FIRST: every compiler-issued vmem (seg/idxn/idxe) is
  // consumed here, before the asm-load region, so hw vmcnt is ours alone.
  const int sprev = __shfl(sv, (lane - 1) & 63);
  const bool head = vl && (lane == 0 || sprev != sv);
  const unsigned long long bal = __ballot(head);
  const int r = (int)__popcll(bal & ((1ull << lane) - 1ull));
  const int r_w = (int)__popcll(bal);

  for (int idx = lane; idx < r_w * LSTR; idx += 64) acc_w[idx] = 0.f;

  const int slot_l = r - (head ? 0 : 1);
  if (head) lds_map[w][slot_l] = (lane << 20) | sv;   // head lane | node id

  int slv[4];
  unsigned woff[4], xoff[4];
  #pragma unroll
  for (int g = 0; g < 4; ++g) {
    const int src = g * 16 + e16;
    const int fg = __shfl(f_l, src);
    const int ng = __shfl(n_l, src);
    slv[g] = __shfl(slot_l, src);
    woff[g] = ((unsigned)fg << 9) | (j << 4);
    xoff[g] = ((unsigned)ng << 6) | (j << 4);
  }

  // ---- asm-load region: depth-2, 9 loads per group, counted waits.
  uvec4 wv0[8], wv1[8], wv2[8], wv3[8];
  fvec4 xo0, xo1, xo2, xo3;
  ISSUE_GROUP(0, wv0, xo0);                // 9 in flight
  ISSUE_GROUP(1, wv1, xo1);                // 18 in flight

  VMWAIT(9);                               // group 0 ready, group 1 in flight
  do_phase(xo0, wv0, slv[0], e16 < valid_cnt, j, acc_w);
  ISSUE_GROUP(2, wv2, xo2);                // 18 in flight

  VMWAIT(9);                               // group 1 ready
  do_phase(xo1, wv1, slv[1], 16 + e16 < valid_cnt, j, acc_w);
  ISSUE_GROUP(3, wv3, xo3);                // 18 in flight

  VMWAIT(9);                               // group 2 ready
  do_phase(xo2, wv2, slv[2], 32 + e16 < valid_cnt, j, acc_w);

  VMWAIT(0);                               // group 3 ready (pipeline drained)
  do_phase(xo3, wv3, slv[3], 48 + e16 < valid_cnt, j, acc_w);

  // drain wave-local DS before reading slots (no barrier: wave-private).
  asm volatile("s_waitcnt lgkmcnt(0)" ::: "memory");

  // flush; deg derived from head-lane deltas (no cnt accumulation).
  const int ch = lane & 15;
  for (int slot = lane >> 4; slot < r_w; slot += 4) {
    const int m0 = lds_map[w][slot];
    const int node = m0 & 0xFFFFF;
    atomicAdd(sums + ((size_t)node << 4) + ch, acc_w[slot * LSTR + ch]);
    if (ch == 0) {
      const int start = m0 >> 20;
      const int end =
          (slot + 1 < r_w) ? (lds_map[w][slot + 1] >> 20) : valid_cnt;
      atomicAdd(deg + node, (float)(end - start));
    }
  }
}

// ---------------- Kernel 3: divide by degree --------------------------------
__global__ __launch_bounds__(256) void finalize_kernel(
    const float* __restrict__ sums, const float* __restrict__ deg,
    float* __restrict__ out, int n_nodes) {
  const int n = blockIdx.x * blockDim.x + threadIdx.x;
  if (n >= n_nodes) return;
  const float d = deg[n];
  const float scale = d > 0.f ? 1.f / d : 0.f;
  const float4* sp = (const float4*)(sums + (size_t)n * OUT_CH);
  float4* op = (float4*)(out + (size_t)n * OUT_CH);
  #pragma unroll
  for (int q = 0; q < 4; ++q) {
    float4 v = sp[q];
    v.x *= scale; v.y *= scale; v.z *= scale; v.w *= scale;
    op[q] = v;
  }
}

extern "C" void kernel_launch(void* const* d_in, const int* in_sizes, int n_in,
                              void* d_out, int out_size, void* d_ws, size_t ws_size,
                              hipStream_t stream) {
  const float* input = (const float*)d_in[0];
  const int* idxn    = (const int*)d_in[1];
  const int* idxe    = (const int*)d_in[2];
  const int* seg     = (const int*)d_in[3];
  const float* ef    = (const float*)d_in[4];
  const float* W1    = (const float*)d_in[5];
  const float* b1    = (const float*)d_in[6];
  const float* W2    = (const float*)d_in[7];
  const float* b2    = (const float*)d_in[8];
  float* out = (float*)d_out;

  const int n_nodes   = in_sizes[0] / IN_CH;
  const int n_edges   = in_sizes[1];
  const int n_filters = in_sizes[4] / EDGE_FEAT;

  // workspace: f16 weights [F*256] (2 MB) | sums [n_nodes*16] | deg [n_nodes]
  unsigned short* weights = (unsigned short*)d_ws;
  float* sums = (float*)((char*)d_ws + (size_t)n_filters * WROW * sizeof(unsigned short));
  float* deg  = sums + (size_t)n_nodes * OUT_CH;

  const int nzero4 = (n_nodes * (OUT_CH + 1)) / 4;
  filter_net_kernel<<<n_filters / FN_FPB, 256, 0, stream>>>(
      ef, W1, b1, W2, b2, weights, sums, nzero4);

  const long n_blocks = ((long)n_edges + 255) / 256;
  edge_kernel<<<(int)n_blocks, 256, 0, stream>>>(
      input, idxn, idxe, seg, weights, sums, deg, n_edges);

  finalize_kernel<<<(n_nodes + 255) / 256, 256, 0, stream>>>(sums, deg, out,
                                                             n_nodes);
}